// Round 7
// baseline (3373.756 us; speedup 1.0000x reference)
//
#include <hip/hip_runtime.h>

// QRNN: T=512, B=32, D=1024, Q=256.
//  Phase A (prep):  build WhT/UhT fp16 [e][d] (transposed); zero flags.
//  Phase B (gemm):  wh_out = x @ Wh + b  -> written fp32 into d_out (overwritten by scan).
//  Phase C (scan):  h_t = tanh(wh_out[t] + h_{t-1} @ Uh), in-place on d_out.
//      64 WGs = 2 row-groups x 32 col-groups; 128 thr/WG (2 waves x 16 cols).
//  R8: the untested protocol cell — per-WAVE per-t flags (fresh 256B line per (r,t)).
//      * R1 (per-WG per-t flags, 2 barriers) = 3007us. R5 (per-wave MONOTONIC flags, 0
//        barriers) = 3195us — but monotonic = 4 hot lines ping-ponged by 128 writers +
//        8192 pollers; the regression is plausibly line contention, not barrier removal.
//      * R8 removes both barriers AND the detect-broadcast hop while keeping fresh flag
//        lines: each wave polls 64 per-wave flags with 64 lanes (ONE coalesced 2-line
//        coherent load per poll iteration) and proceeds to its payload loads immediately.
//      * Producer per wave: epilogue -> 4 ring u32 stores -> vmcnt(0) (ring acks only;
//        R7 proved HBM stores after-publish is safe/neutral) -> lane0 flag store.
//      * Reuse safety (R1 argument): wave at t saw all t-1 flags; each flag was stored
//        after that wave's drain, which retired its slot-(t-2) reads; my slot-(t&1)
//        stores issue after my poll load of that flag. Transitive.
//  All inter-WG traffic via per-access coherent atomics (sc0 sc1 -> LLC). No agent
//  fences (they compile to whole-L2 buffer_inv/buffer_wbl2).

#define TT 512
#define BB 32
#define DD 1024

typedef _Float16 f16;
typedef _Float16 f16x8 __attribute__((ext_vector_type(8)));
typedef _Float16 f16x4 __attribute__((ext_vector_type(4)));
typedef float f32x4 __attribute__((ext_vector_type(4)));
typedef unsigned long long u64;

__device__ __constant__ int   QCOMP[4][4] = {{0,1,2,3},{1,0,3,2},{2,3,0,1},{3,2,1,0}};
__device__ __constant__ float QSIGN[4][4] = {{ 1.f, 1.f, 1.f, 1.f},
                                             {-1.f, 1.f, 1.f,-1.f},
                                             {-1.f,-1.f, 1.f, 1.f},
                                             {-1.f, 1.f,-1.f, 1.f}};

__device__ __forceinline__ float qpick(int cmp, const float* a, const float* b,
                                       const float* c, const float* d, int idx) {
    const float* s = (cmp == 0) ? a : (cmp == 1) ? b : (cmp == 2) ? c : d;
    return s[idx];
}

// ---------------- Phase A -------------------------------------------------------------
__global__ void qrnn_prep(const float* __restrict__ wr, const float* __restrict__ wi,
                          const float* __restrict__ wj, const float* __restrict__ wk,
                          const float* __restrict__ ur, const float* __restrict__ ui,
                          const float* __restrict__ uj, const float* __restrict__ uk,
                          f16* __restrict__ WhT, f16* __restrict__ UhT,
                          int* __restrict__ flags)
{
    int bid = blockIdx.x;
    int gid = bid * 256 + threadIdx.x;
    if (bid < 4096) {                    // WhT: 1M elements, flat = e*1024 + d
        int e = gid >> 10, d = gid & 1023;
        int bc = e >> 8, j = e & 255, br = d >> 8, i = d & 255;
        float v = QSIGN[br][bc] * qpick(QCOMP[br][bc], wr, wi, wj, wk, i * 256 + j);
        WhT[gid] = (f16)v;
    } else if (bid < 8192) {             // UhT
        int g = gid - 4096 * 256;
        int e = g >> 10, d = g & 1023;
        int bc = e >> 8, j = e & 255, br = d >> 8, i = d & 255;
        float v = QSIGN[br][bc] * qpick(QCOMP[br][bc], ur, ui, uj, uk, i * 256 + j);
        UhT[g] = (f16)v;
    } else {                             // flags: 2 rowgroups x 512 t x 64 waves -> zero
        int g = gid - 8192 * 256;
        if (g < 2 * 512 * 64) flags[g] = 0;
    }
}

// ---------------- Phase B: wh_out = x @ Wh + bias ------------------------------------
__global__ __launch_bounds__(256) void qrnn_gemm(const float* __restrict__ x,
                                                 const f16* __restrict__ WhT,
                                                 const float* __restrict__ bias,
                                                 float* __restrict__ out)
{
    __shared__ f16 Ash[128][72];
    __shared__ f16 Bsh[128][72];

    const int tn = blockIdx.x, tm = blockIdx.y;
    const int tid = threadIdx.x;
    const int lane = tid & 63, w = tid >> 6;
    const int wm = (w >> 1) * 64, wn = (w & 1) * 64;
    const int m0 = tm * 128, n0 = tn * 128;
    const int l15 = lane & 15, q8 = (lane >> 4) * 8;

    f32x4 acc[4][4] = {};

    const int arow = tid >> 4;
    const int acol = (tid & 15) * 4;
    const int brow = tid >> 3;
    const int bcol = (tid & 7) * 8;

    for (int kb = 0; kb < DD; kb += 64) {
        #pragma unroll
        for (int p = 0; p < 8; ++p) {
            int rrow = p * 16 + arow;
            float4 v = *(const float4*)(x + (size_t)(m0 + rrow) * DD + kb + acol);
            f16x4 hv = {(f16)v.x, (f16)v.y, (f16)v.z, (f16)v.w};
            *(f16x4*)&Ash[rrow][acol] = hv;
        }
        #pragma unroll
        for (int p = 0; p < 4; ++p) {
            int rn = p * 32 + brow;
            f16x8 v = *(const f16x8*)(WhT + (size_t)(n0 + rn) * DD + kb + bcol);
            *(f16x8*)&Bsh[rn][bcol] = v;
        }
        __syncthreads();
        #pragma unroll
        for (int ks = 0; ks < 64; ks += 32) {
            f16x8 af[4], bf[4];
            #pragma unroll
            for (int i = 0; i < 4; ++i) af[i] = *(const f16x8*)&Ash[wm + i * 16 + l15][ks + q8];
            #pragma unroll
            for (int i = 0; i < 4; ++i) bf[i] = *(const f16x8*)&Bsh[wn + i * 16 + l15][ks + q8];
            #pragma unroll
            for (int i = 0; i < 4; ++i)
                #pragma unroll
                for (int j = 0; j < 4; ++j)
                    acc[i][j] = __builtin_amdgcn_mfma_f32_16x16x32_f16(af[i], bf[j], acc[i][j], 0, 0, 0);
        }
        __syncthreads();
    }
    const int quad = lane >> 4;
    #pragma unroll
    for (int i = 0; i < 4; ++i)
        #pragma unroll
        for (int j = 0; j < 4; ++j) {
            int col = n0 + wn + j * 16 + l15;
            float bz = bias[col];
            #pragma unroll
            for (int rr = 0; rr < 4; ++rr) {
                int row = m0 + wm + i * 16 + quad * 4 + rr;
                out[(size_t)row * DD + col] = acc[i][j][rr] + bz;
            }
        }
}

// ---------------- Phase C: sequential scan -------------------------------------------
// WG (r,c): batch rows [16r,16r+16), cols [32c,32c+32). Wave w: 16 cols.
// Per-wave per-t flags; ZERO barriers in the t-loop; each wave fully independent.
__global__ __launch_bounds__(128, 1) void qrnn_scan(const f16* __restrict__ UhT,
                                                    unsigned int* __restrict__ hbuf,
                                                    int* __restrict__ flags,
                                                    float* __restrict__ out)
{
    __shared__ f16 Ush[32][1032];   // 32 cols x 1024 k, +8 pad (2-way bank alias = free)

    const int r = blockIdx.x >> 5;          // row group 0..1
    const int c = blockIdx.x & 31;          // col group 0..31
    const int tid = threadIdx.x;
    const int w = tid >> 6, lane = tid & 63;
    const int l15 = lane & 15, quad = lane >> 4, q8 = quad * 8;
    const int dcol = c * 32 + w * 16 + l15; // output feature col (D-frag n)
    const int bq = r * 16 + quad * 4;       // first output batch row (D-frag)

    // stage Uh slice -> LDS: each thread 256 halves of one row
    {
        const int nl = tid >> 2, k0 = (tid & 3) * 256;
        const f16* src = UhT + (size_t)(c * 32 + nl) * DD + k0;
        #pragma unroll
        for (int p = 0; p < 32; ++p)
            *(f16x8*)&Ush[nl][k0 + p * 8] = *(const f16x8*)(src + p * 8);
    }
    __syncthreads();   // only barrier in the kernel (Ush read-only afterwards)

    const int nloc = w * 16 + l15;          // local col for B-frag reads

    // comm buffer geometry (fp16 elements addressed via u32/u64)
    // element idx = row*1024 + k ; byte = idx*2 ; buffers at parity*65536 bytes
    char* hb = (char*)hbuf;
    const char* harow = hb + (size_t)((r * 16 + l15) * 1024 + q8) * 2;  // A[m][k] m=l15
    char* hwrow = hb + (size_t)(bq * 1024 + (dcol & ~1)) * 2;           // packed u32 store base

    // flags layout: [(r*512 + t)*64 + waveid], waveid = c*2 + w. Fresh 256B line per (r,t).
    const int waveid = (c << 1) + w;

    #pragma unroll 1
    for (int t = 0; t < TT; ++t) {
        const size_t obase = (size_t)t * (BB * DD) + (size_t)bq * DD + dcol;

        // wh at loop top: consumer-local latency, overlapped with the flag poll below
        float wh[4];
        #pragma unroll
        for (int i = 0; i < 4; ++i) wh[i] = out[obase + (size_t)i * DD];

        f32x4 acc[4] = {};
        if (t > 0) {
            // each wave polls independently: lane l <-> producer-wave l of this row group
            const int* fp = flags + (((r << 9) + (t - 1)) << 6) + lane;
            while (__hip_atomic_load(fp, __ATOMIC_RELAXED, __HIP_MEMORY_SCOPE_AGENT) == 0) {
                __builtin_amdgcn_s_sleep(1);
            }
            // no barrier: this wave proceeds the instant its own poll clears

            const char* ha = harow + ((t - 1) & 1) * 65536;
            #pragma unroll
            for (int u = 0; u < 32; ++u) {
                union { u64 q[2]; f16x8 v; } uu;
                uu.q[0] = __hip_atomic_load((const u64*)(ha + u * 64),
                                            __ATOMIC_RELAXED, __HIP_MEMORY_SCOPE_AGENT);
                uu.q[1] = __hip_atomic_load((const u64*)(ha + u * 64 + 8),
                                            __ATOMIC_RELAXED, __HIP_MEMORY_SCOPE_AGENT);
                f16x8 bf = *(const f16x8*)&Ush[nloc][u * 32 + q8];
                acc[u & 3] = __builtin_amdgcn_mfma_f32_16x16x32_f16(uu.v, bf, acc[u & 3], 0, 0, 0);
            }
        }

        // epilogue: compute h; publish ring, per-wave drain (ring LLC acks only), flag.
        float hv[4];
        #pragma unroll
        for (int i = 0; i < 4; ++i) {
            float z = (acc[0][i] + acc[1][i]) + (acc[2][i] + acc[3][i]) + wh[i];
            float e = __expf(2.0f * z);
            hv[i] = 1.0f - 2.0f * __builtin_amdgcn_rcpf(e + 1.0f);
        }

        if (t < TT - 1) {
            char* hwp = hwrow + (t & 1) * 65536;
            #pragma unroll
            for (int i = 0; i < 4; ++i) {
                f16 hh = (f16)hv[i];
                unsigned short hbits = __builtin_bit_cast(unsigned short, hh);
                int other = __shfl_xor((int)hbits, 1, 64);   // partner col (l15 ^ 1)
                if ((lane & 1) == 0) {
                    unsigned int packed = (unsigned int)hbits | ((unsigned int)other << 16);
                    __hip_atomic_store((unsigned int*)(hwp + (size_t)i * 2048), packed,
                                       __ATOMIC_RELAXED, __HIP_MEMORY_SCOPE_AGENT);
                }
            }
            // per-wave drain: frag loads already retired (consumed), previous out stores
            // retired under the poll -> only this wave's 4 ring stores are outstanding.
            asm volatile("s_waitcnt vmcnt(0)" ::: "memory");
            if (lane == 0)
                __hip_atomic_store(flags + (((r << 9) + t) << 6) + waveid, 1,
                                   __ATOMIC_RELAXED, __HIP_MEMORY_SCOPE_AGENT);
            __builtin_amdgcn_sched_barrier(0);   // keep out stores below the publish
        }

        // fp32 h -> d_out AFTER publish: HBM acks retire lazily under the next poll.
        #pragma unroll
        for (int i = 0; i < 4; ++i) out[obase + (size_t)i * DD] = hv[i];
    }
}

extern "C" void kernel_launch(void* const* d_in, const int* in_sizes, int n_in,
                              void* d_out, int out_size, void* d_ws, size_t ws_size,
                              hipStream_t stream)
{
    const float* x  = (const float*)d_in[0];
    const float* wr = (const float*)d_in[1];
    const float* wi = (const float*)d_in[2];
    const float* wj = (const float*)d_in[3];
    const float* wk = (const float*)d_in[4];
    const float* ur = (const float*)d_in[5];
    const float* ui = (const float*)d_in[6];
    const float* uj = (const float*)d_in[7];
    const float* uk = (const float*)d_in[8];
    const float* bias = (const float*)d_in[9];
    float* out = (float*)d_out;

    char* ws = (char*)d_ws;
    f16* WhT  = (f16*)(ws);                          // 2 MB
    f16* UhT  = (f16*)(ws + (1 << 21));              // 2 MB
    unsigned int* hbuf = (unsigned int*)(ws + (1 << 22));      // 2 x 64 KB
    int* flags = (int*)(ws + (1 << 22) + (1 << 17)); // 65536 ints (per-wave per-t)

    hipLaunchKernelGGL(qrnn_prep, dim3(8448), dim3(256), 0, stream,
                       wr, wi, wj, wk, ur, ui, uj, uk, WhT, UhT, flags);
    hipLaunchKernelGGL(qrnn_gemm, dim3(8, 128), dim3(256), 0, stream,
                       x, WhT, bias, out);
    hipLaunchKernelGGL(qrnn_scan, dim3(64), dim3(128), 0, stream,
                       UhT, hbuf, flags, out);
}

// Round 8
// 2534.520 us; speedup vs baseline: 1.3311x; 1.3311x over previous
//
#include <hip/hip_runtime.h>

// QRNN: T=512, B=32, D=1024, Q=256.
//  Phase A (prep):  build WhT/UhT fp16 [e][d] (transposed); zero flags.
//  Phase B (gemm):  wh_out = x @ Wh + b  -> written fp32 into d_out (overwritten by scan).
//  Phase C (scan):  h_t = tanh(wh_out[t] + h_{t-1} @ Uh), in-place on d_out.
//  R9: TOPOLOGY restructure (protocol matrix R1/R5/R7/R8 proved flat 3007-3195; sentinel
//      worse; R6 showed coherent-read volume costs ~1.4us/step per 2x — attack traffic).
//      16 WGs = 2 row-groups x 8 col-groups; 512 thr/WG (8 waves x 16 cols each).
//        * Uh LIVES IN REGISTERS: per wave 32 B-frags (16 cols x 1024 k) = 128 VGPRs,
//          loaded once from UhT at start. LDS freed for h.
//        * h staged ONCE PER WG into LDS (32KB coherent coop-load, 8B/thread x 8),
//          XOR-swizzled (byte ^= (row&7)<<4) so A-frag ds_read_b128 is conflict-free.
//          Coherent reads: 4MB/step (128 wave-pulls) -> 512KB/step (16 WG-pulls).
//        * Producers per row group: 8 (was 32) -> max-order-statistic wait shrinks.
//      Protocol = R1's proven best: per-WG per-t flags, tid<8 poll, barriers, ring-only
//      drain, out stores after publish. Reuse safety: flag(t-1,L)=1 implies L's vmcnt(0)
//      drained, which covers L's staging LOADS of slot t&1 -> writer at t can't corrupt.
//  All inter-WG traffic via per-access coherent atomics (sc0 sc1 -> LLC). No agent fences.

#define TT 512
#define BB 32
#define DD 1024

typedef _Float16 f16;
typedef _Float16 f16x8 __attribute__((ext_vector_type(8)));
typedef _Float16 f16x4 __attribute__((ext_vector_type(4)));
typedef float f32x4 __attribute__((ext_vector_type(4)));
typedef unsigned long long u64;

__device__ __constant__ int   QCOMP[4][4] = {{0,1,2,3},{1,0,3,2},{2,3,0,1},{3,2,1,0}};
__device__ __constant__ float QSIGN[4][4] = {{ 1.f, 1.f, 1.f, 1.f},
                                             {-1.f, 1.f, 1.f,-1.f},
                                             {-1.f,-1.f, 1.f, 1.f},
                                             {-1.f, 1.f,-1.f, 1.f}};

__device__ __forceinline__ float qpick(int cmp, const float* a, const float* b,
                                       const float* c, const float* d, int idx) {
    const float* s = (cmp == 0) ? a : (cmp == 1) ? b : (cmp == 2) ? c : d;
    return s[idx];
}

// ---------------- Phase A -------------------------------------------------------------
__global__ void qrnn_prep(const float* __restrict__ wr, const float* __restrict__ wi,
                          const float* __restrict__ wj, const float* __restrict__ wk,
                          const float* __restrict__ ur, const float* __restrict__ ui,
                          const float* __restrict__ uj, const float* __restrict__ uk,
                          f16* __restrict__ WhT, f16* __restrict__ UhT,
                          int* __restrict__ flags)
{
    int bid = blockIdx.x;
    int gid = bid * 256 + threadIdx.x;
    if (bid < 4096) {                    // WhT: 1M elements, flat = e*1024 + d
        int e = gid >> 10, d = gid & 1023;
        int bc = e >> 8, j = e & 255, br = d >> 8, i = d & 255;
        float v = QSIGN[br][bc] * qpick(QCOMP[br][bc], wr, wi, wj, wk, i * 256 + j);
        WhT[gid] = (f16)v;
    } else if (bid < 8192) {             // UhT
        int g = gid - 4096 * 256;
        int e = g >> 10, d = g & 1023;
        int bc = e >> 8, j = e & 255, br = d >> 8, i = d & 255;
        float v = QSIGN[br][bc] * qpick(QCOMP[br][bc], ur, ui, uj, uk, i * 256 + j);
        UhT[g] = (f16)v;
    } else {                             // flags: 2 rowgroups x 512 t x 8 cg = 8192 ints
        int g = (bid - 8192) * 256 + threadIdx.x;
        if (g < 8192) flags[g] = 0;
    }
}

// ---------------- Phase B: wh_out = x @ Wh + bias ------------------------------------
__global__ __launch_bounds__(256) void qrnn_gemm(const float* __restrict__ x,
                                                 const f16* __restrict__ WhT,
                                                 const float* __restrict__ bias,
                                                 float* __restrict__ out)
{
    __shared__ f16 Ash[128][72];
    __shared__ f16 Bsh[128][72];

    const int tn = blockIdx.x, tm = blockIdx.y;
    const int tid = threadIdx.x;
    const int lane = tid & 63, w = tid >> 6;
    const int wm = (w >> 1) * 64, wn = (w & 1) * 64;
    const int m0 = tm * 128, n0 = tn * 128;
    const int l15 = lane & 15, q8 = (lane >> 4) * 8;

    f32x4 acc[4][4] = {};

    const int arow = tid >> 4;
    const int acol = (tid & 15) * 4;
    const int brow = tid >> 3;
    const int bcol = (tid & 7) * 8;

    for (int kb = 0; kb < DD; kb += 64) {
        #pragma unroll
        for (int p = 0; p < 8; ++p) {
            int rrow = p * 16 + arow;
            float4 v = *(const float4*)(x + (size_t)(m0 + rrow) * DD + kb + acol);
            f16x4 hv = {(f16)v.x, (f16)v.y, (f16)v.z, (f16)v.w};
            *(f16x4*)&Ash[rrow][acol] = hv;
        }
        #pragma unroll
        for (int p = 0; p < 4; ++p) {
            int rn = p * 32 + brow;
            f16x8 v = *(const f16x8*)(WhT + (size_t)(n0 + rn) * DD + kb + bcol);
            *(f16x8*)&Bsh[rn][bcol] = v;
        }
        __syncthreads();
        #pragma unroll
        for (int ks = 0; ks < 64; ks += 32) {
            f16x8 af[4], bf[4];
            #pragma unroll
            for (int i = 0; i < 4; ++i) af[i] = *(const f16x8*)&Ash[wm + i * 16 + l15][ks + q8];
            #pragma unroll
            for (int i = 0; i < 4; ++i) bf[i] = *(const f16x8*)&Bsh[wn + i * 16 + l15][ks + q8];
            #pragma unroll
            for (int i = 0; i < 4; ++i)
                #pragma unroll
                for (int j = 0; j < 4; ++j)
                    acc[i][j] = __builtin_amdgcn_mfma_f32_16x16x32_f16(af[i], bf[j], acc[i][j], 0, 0, 0);
        }
        __syncthreads();
    }
    const int quad = lane >> 4;
    #pragma unroll
    for (int i = 0; i < 4; ++i)
        #pragma unroll
        for (int j = 0; j < 4; ++j) {
            int col = n0 + wn + j * 16 + l15;
            float bz = bias[col];
            #pragma unroll
            for (int rr = 0; rr < 4; ++rr) {
                int row = m0 + wm + i * 16 + quad * 4 + rr;
                out[(size_t)row * DD + col] = acc[i][j][rr] + bz;
            }
        }
}

// ---------------- Phase C: sequential scan (16 WGs x 8 waves, Uh-in-regs) ------------
// WG (rg,cg): batch rows [16rg,16rg+16), cols [128cg,128cg+128). Wave w: 16 cols.
// Ring: 2 slots x 64KB, layout [32 rows][1024 cols] fp16 (byte = (row*1024+col)*2).
__global__ __launch_bounds__(512, 2) void qrnn_scan(const f16* __restrict__ UhT,
                                                    unsigned int* __restrict__ hbuf,
                                                    int* __restrict__ flags,
                                                    float* __restrict__ out)
{
    __shared__ u64 HshQ[4096];              // 32KB: h block, XOR-swizzled rows
    char* Hsh = (char*)HshQ;

    const int rg = blockIdx.x >> 3;         // row group 0..1
    const int cg = blockIdx.x & 7;          // col group 0..7
    const int tid = threadIdx.x;
    const int w = tid >> 6, lane = tid & 63;
    const int l15 = lane & 15, quad = lane >> 4, q8 = quad * 8;
    const int dcol = cg * 128 + w * 16 + l15;   // output feature col
    const int bq = rg * 16 + quad * 4;          // first output batch row of this frag

    // ---- one-time: Uh B-fragments into registers (16 cols x 1024 k per wave) ----
    f16x8 bfr[32];
    {
        const f16* ub = UhT + (size_t)dcol * DD;
        #pragma unroll
        for (int u = 0; u < 32; ++u)
            bfr[u] = *(const f16x8*)(ub + u * 32 + q8);
    }

    char* hb = (char*)hbuf;
    char* hwrow = hb + (size_t)(bq * 1024 + (dcol & ~1)) * 2;   // packed u32 store base

    // staging geometry: thread reads 8x u64 at src + j*4096; dest row/k2 derived below
    const int srow0 = tid >> 8;                 // + j*2
    const int sk2   = (tid & 255) * 8;          // byte offset within row

    // A-frag read geometry: row = l15, k-bytes = u*64 + quad*16, XOR (row&7)<<4
    const int abase = l15 * 2048;
    const int axor  = (l15 & 7) << 4;

    #pragma unroll 1
    for (int t = 0; t < TT; ++t) {
        const size_t obase = (size_t)t * (BB * DD) + (size_t)bq * DD + dcol;

        // wh at loop top: consumer-local, retires under the poll spin
        float wh[4];
        #pragma unroll
        for (int i = 0; i < 4; ++i) wh[i] = out[obase + (size_t)i * DD];

        f32x4 acc[4] = {};
        if (t > 0) {
            if (tid < 8) {
                const int* fp = flags + ((rg * 512 + (t - 1)) * 8) + tid;
                while (__hip_atomic_load(fp, __ATOMIC_RELAXED, __HIP_MEMORY_SCOPE_AGENT) == 0) {
                    __builtin_amdgcn_s_sleep(1);
                }
            }
            __syncthreads();   // all 8 producer flags seen

            // ---- cooperative coherent load of this rg's 32KB h block -> swizzled LDS ----
            const char* src = hb + (size_t)((t - 1) & 1) * 65536 + (size_t)rg * 32768 + tid * 8;
            #pragma unroll
            for (int j = 0; j < 8; ++j) {
                u64 v = __hip_atomic_load((const u64*)(src + (size_t)j * 4096),
                                          __ATOMIC_RELAXED, __HIP_MEMORY_SCOPE_AGENT);
                int row = srow0 + j * 2;
                *(u64*)(Hsh + row * 2048 + (sk2 ^ ((row & 7) << 4))) = v;
            }
            __syncthreads();   // staging complete

            // ---- 32 MFMAs: A from swizzled LDS, B from registers ----
            #pragma unroll
            for (int u = 0; u < 32; ++u) {
                f16x8 af = *(const f16x8*)(Hsh + abase + ((u * 64 + quad * 16) ^ axor));
                acc[u & 3] = __builtin_amdgcn_mfma_f32_16x16x32_f16(af, bfr[u], acc[u & 3], 0, 0, 0);
            }
        }

        // epilogue: compute h
        float hv[4];
        #pragma unroll
        for (int i = 0; i < 4; ++i) {
            float z = (acc[0][i] + acc[1][i]) + (acc[2][i] + acc[3][i]) + wh[i];
            float e = __expf(2.0f * z);
            hv[i] = 1.0f - 2.0f * __builtin_amdgcn_rcpf(e + 1.0f);
        }

        if (t < TT - 1) {
            // publish fp16 to ring slot t&1 (packed u32 via partner-lane shfl)
            char* hwp = hwrow + (size_t)(t & 1) * 65536;
            #pragma unroll
            for (int i = 0; i < 4; ++i) {
                f16 hh = (f16)hv[i];
                unsigned short hbits = __builtin_bit_cast(unsigned short, hh);
                int other = __shfl_xor((int)hbits, 1, 64);   // partner col (l15 ^ 1)
                if ((lane & 1) == 0) {
                    unsigned int packed = (unsigned int)hbits | ((unsigned int)other << 16);
                    __hip_atomic_store((unsigned int*)(hwp + (size_t)i * 2048), packed,
                                       __ATOMIC_RELAXED, __HIP_MEMORY_SCOPE_AGENT);
                }
            }
            // ring-only drain (staging loads long retired; out stores retired under poll)
            asm volatile("s_waitcnt vmcnt(0)" ::: "memory");
            __syncthreads();                                   // all 8 waves drained
            if (tid == 0)
                __hip_atomic_store(flags + ((rg * 512 + t) * 8) + cg, 1,
                                   __ATOMIC_RELAXED, __HIP_MEMORY_SCOPE_AGENT);
            __builtin_amdgcn_sched_barrier(0);   // keep out stores below the publish
        }

        // fp32 h -> d_out AFTER publish: HBM acks retire lazily under the next poll
        #pragma unroll
        for (int i = 0; i < 4; ++i) out[obase + (size_t)i * DD] = hv[i];
    }
}

extern "C" void kernel_launch(void* const* d_in, const int* in_sizes, int n_in,
                              void* d_out, int out_size, void* d_ws, size_t ws_size,
                              hipStream_t stream)
{
    const float* x  = (const float*)d_in[0];
    const float* wr = (const float*)d_in[1];
    const float* wi = (const float*)d_in[2];
    const float* wj = (const float*)d_in[3];
    const float* wk = (const float*)d_in[4];
    const float* ur = (const float*)d_in[5];
    const float* ui = (const float*)d_in[6];
    const float* uj = (const float*)d_in[7];
    const float* uk = (const float*)d_in[8];
    const float* bias = (const float*)d_in[9];
    float* out = (float*)d_out;

    char* ws = (char*)d_ws;
    f16* WhT  = (f16*)(ws);                          // 2 MB
    f16* UhT  = (f16*)(ws + (1 << 21));              // 2 MB
    unsigned int* hbuf = (unsigned int*)(ws + (1 << 22));      // 2 x 64 KB
    int* flags = (int*)(ws + (1 << 22) + (1 << 17)); // 8192 ints

    hipLaunchKernelGGL(qrnn_prep, dim3(8224), dim3(256), 0, stream,
                       wr, wi, wj, wk, ur, ui, uj, uk, WhT, UhT, flags);
    hipLaunchKernelGGL(qrnn_gemm, dim3(8, 128), dim3(256), 0, stream,
                       x, WhT, bias, out);
    hipLaunchKernelGGL(qrnn_scan, dim3(16), dim3(512), 0, stream,
                       UhT, hbuf, flags, out);
}

// Round 9
// 2106.933 us; speedup vs baseline: 1.6013x; 1.2029x over previous
//
#include <hip/hip_runtime.h>

// QRNN: T=512, B=32, D=1024, Q=256.
//  Phase A (prep):  build WhT/UhT fp16 [e][d] (transposed); fill hbuf ring with sentinel.
//  Phase B (gemm):  wh_out = x @ Wh + b  -> written fp32 into d_out (overwritten by scan).
//  Phase C (scan):  h_t = tanh(wh_out[t] + h_{t-1} @ Uh), in-place on d_out.
//  R10 = R9 staged topology (16 WGs = 2rg x 8cg, 512thr, Uh-in-regs(AGPRs), h staged
//        once per WG into swizzled LDS — 3007->2351us) + SENTINEL handshake:
//    * Validity embedded in data (tanh can't be fp16 NaN 0x7E00). Producer path ends at
//      "4 u32 coherent stores issued": NO drain RT, NO flag leg, NO poll-detect leg.
//    * Consumer: coop-load 8 u64/thread, validate 16 u32s in regs, retry ONLY bad u64s,
//      converge via __syncthreads_or (its exit barrier doubles as the MFMA-read-complete
//      barrier before ds_write). R3/R6's sentinel regressed in the 128-wave-pull topology
//      (4MB/retry-round); staged topology is 8x cheaper per round and single-round-common.
//    * Reuse safety: every step's staging vmcnt wait bounds the wave's older stores
//      (in-order retirement) incl. re-sentinels; validation of h_{t-1} transitively
//      orders all waves past their step-(t-3) re-sentinel. 8-slot ring, distance-3
//      re-sentinel — schedule correctness-proven in R3/R6.
//  All inter-WG traffic via per-access coherent atomics (sc0 sc1 -> LLC). No agent fences.

#define TT 512
#define BB 32
#define DD 1024
#define SENT32 0x7E007E00u

typedef _Float16 f16;
typedef _Float16 f16x8 __attribute__((ext_vector_type(8)));
typedef _Float16 f16x4 __attribute__((ext_vector_type(4)));
typedef float f32x4 __attribute__((ext_vector_type(4)));
typedef unsigned int u32;
typedef unsigned long long u64;

__device__ __constant__ int   QCOMP[4][4] = {{0,1,2,3},{1,0,3,2},{2,3,0,1},{3,2,1,0}};
__device__ __constant__ float QSIGN[4][4] = {{ 1.f, 1.f, 1.f, 1.f},
                                             {-1.f, 1.f, 1.f,-1.f},
                                             {-1.f,-1.f, 1.f, 1.f},
                                             {-1.f, 1.f,-1.f, 1.f}};

__device__ __forceinline__ float qpick(int cmp, const float* a, const float* b,
                                       const float* c, const float* d, int idx) {
    const float* s = (cmp == 0) ? a : (cmp == 1) ? b : (cmp == 2) ? c : d;
    return s[idx];
}

// ---------------- Phase A -------------------------------------------------------------
__global__ void qrnn_prep(const float* __restrict__ wr, const float* __restrict__ wi,
                          const float* __restrict__ wj, const float* __restrict__ wk,
                          const float* __restrict__ ur, const float* __restrict__ ui,
                          const float* __restrict__ uj, const float* __restrict__ uk,
                          f16* __restrict__ WhT, f16* __restrict__ UhT,
                          unsigned int* __restrict__ hbuf)
{
    int bid = blockIdx.x;
    int gid = bid * 256 + threadIdx.x;
    if (bid < 4096) {                    // WhT: 1M elements, flat = e*1024 + d
        int e = gid >> 10, d = gid & 1023;
        int bc = e >> 8, j = e & 255, br = d >> 8, i = d & 255;
        float v = QSIGN[br][bc] * qpick(QCOMP[br][bc], wr, wi, wj, wk, i * 256 + j);
        WhT[gid] = (f16)v;
    } else if (bid < 8192) {             // UhT
        int g = gid - 4096 * 256;
        int e = g >> 10, d = g & 1023;
        int bc = e >> 8, j = e & 255, br = d >> 8, i = d & 255;
        float v = QSIGN[br][bc] * qpick(QCOMP[br][bc], ur, ui, uj, uk, i * 256 + j);
        UhT[g] = (f16)v;
    } else {                             // hbuf sentinel fill: 8 slots x 64KB = 32768 uint4
        int g = gid - 8192 * 256;        // (kernel-end L2 writeback makes these visible
        if (g < 32768) {                 //  to scan's coherent LLC reads — R3/R6-proven)
            uint4 s = {SENT32, SENT32, SENT32, SENT32};
            ((uint4*)hbuf)[g] = s;
        }
    }
}

// ---------------- Phase B: wh_out = x @ Wh + bias ------------------------------------
__global__ __launch_bounds__(256) void qrnn_gemm(const float* __restrict__ x,
                                                 const f16* __restrict__ WhT,
                                                 const float* __restrict__ bias,
                                                 float* __restrict__ out)
{
    __shared__ f16 Ash[128][72];
    __shared__ f16 Bsh[128][72];

    const int tn = blockIdx.x, tm = blockIdx.y;
    const int tid = threadIdx.x;
    const int lane = tid & 63, w = tid >> 6;
    const int wm = (w >> 1) * 64, wn = (w & 1) * 64;
    const int m0 = tm * 128, n0 = tn * 128;
    const int l15 = lane & 15, q8 = (lane >> 4) * 8;

    f32x4 acc[4][4] = {};

    const int arow = tid >> 4;
    const int acol = (tid & 15) * 4;
    const int brow = tid >> 3;
    const int bcol = (tid & 7) * 8;

    for (int kb = 0; kb < DD; kb += 64) {
        #pragma unroll
        for (int p = 0; p < 8; ++p) {
            int rrow = p * 16 + arow;
            float4 v = *(const float4*)(x + (size_t)(m0 + rrow) * DD + kb + acol);
            f16x4 hv = {(f16)v.x, (f16)v.y, (f16)v.z, (f16)v.w};
            *(f16x4*)&Ash[rrow][acol] = hv;
        }
        #pragma unroll
        for (int p = 0; p < 4; ++p) {
            int rn = p * 32 + brow;
            f16x8 v = *(const f16x8*)(WhT + (size_t)(n0 + rn) * DD + kb + bcol);
            *(f16x8*)&Bsh[rn][bcol] = v;
        }
        __syncthreads();
        #pragma unroll
        for (int ks = 0; ks < 64; ks += 32) {
            f16x8 af[4], bf[4];
            #pragma unroll
            for (int i = 0; i < 4; ++i) af[i] = *(const f16x8*)&Ash[wm + i * 16 + l15][ks + q8];
            #pragma unroll
            for (int i = 0; i < 4; ++i) bf[i] = *(const f16x8*)&Bsh[wn + i * 16 + l15][ks + q8];
            #pragma unroll
            for (int i = 0; i < 4; ++i)
                #pragma unroll
                for (int j = 0; j < 4; ++j)
                    acc[i][j] = __builtin_amdgcn_mfma_f32_16x16x32_f16(af[i], bf[j], acc[i][j], 0, 0, 0);
        }
        __syncthreads();
    }
    const int quad = lane >> 4;
    #pragma unroll
    for (int i = 0; i < 4; ++i)
        #pragma unroll
        for (int j = 0; j < 4; ++j) {
            int col = n0 + wn + j * 16 + l15;
            float bz = bias[col];
            #pragma unroll
            for (int rr = 0; rr < 4; ++rr) {
                int row = m0 + wm + i * 16 + quad * 4 + rr;
                out[(size_t)row * DD + col] = acc[i][j][rr] + bz;
            }
        }
}

// ---------------- Phase C: sequential scan (staged + sentinel) -----------------------
// WG (rg,cg): batch rows [16rg,16rg+16), cols [128cg,128cg+128). 8 waves x 16 cols.
// Ring: 8 slots x 64KB, slot layout [32 rows][1024 cols] fp16; rg offset = rg*32768.
__global__ __launch_bounds__(512, 2) void qrnn_scan(const f16* __restrict__ UhT,
                                                    unsigned int* __restrict__ hbuf,
                                                    float* __restrict__ out)
{
    __shared__ u64 HshQ[4096];              // 32KB: h block, XOR-swizzled rows
    char* Hsh = (char*)HshQ;

    const int rg = blockIdx.x >> 3;         // row group 0..1
    const int cg = blockIdx.x & 7;          // col group 0..7
    const int tid = threadIdx.x;
    const int w = tid >> 6, lane = tid & 63;
    const int l15 = lane & 15, quad = lane >> 4, q8 = quad * 8;
    const int dcol = cg * 128 + w * 16 + l15;   // output feature col
    const int bq = rg * 16 + quad * 4;          // first output batch row of this frag

    // ---- one-time: Uh B-fragments into registers/AGPRs (16 cols x 1024 k per wave) ----
    f16x8 bfr[32];
    {
        const f16* ub = UhT + (size_t)dcol * DD;
        #pragma unroll
        for (int u = 0; u < 32; ++u)
            bfr[u] = *(const f16x8*)(ub + u * 32 + q8);
    }

    char* hb = (char*)hbuf;
    char* hwrow = hb + (size_t)(bq * 1024 + (dcol & ~1)) * 2;   // packed u32 store base

    // staging geometry: thread j-th u64 at slot + rg*32768 + tid*8 + j*4096
    const size_t sbase = (size_t)rg * 32768 + (size_t)tid * 8;
    const int srow0 = tid >> 8;                 // dest row = srow0 + j*2
    const int sk2   = (tid & 255) * 8;          // byte offset within row

    // A-frag read geometry: row = l15, k-bytes = u*64 + quad*16, XOR (row&7)<<4
    const int abase = l15 * 2048;
    const int axor  = (l15 & 7) << 4;

    #pragma unroll 1
    for (int t = 0; t < TT; ++t) {
        const size_t obase = (size_t)t * (BB * DD) + (size_t)bq * DD + dcol;

        // wh at loop top: consumer-local, retires under the staging wait
        float wh[4];
        #pragma unroll
        for (int i = 0; i < 4; ++i) wh[i] = out[obase + (size_t)i * DD];

        f32x4 acc[4] = {};
        if (t > 0) {
            const char* src = hb + (size_t)((t - 1) & 7) * 65536 + sbase;
            u64 A[8];
            #pragma unroll
            for (int j = 0; j < 8; ++j)
                A[j] = __hip_atomic_load((const u64*)(src + (size_t)j * 4096),
                                         __ATOMIC_RELAXED, __HIP_MEMORY_SCOPE_AGENT);
            // validate in registers; retry only bad u64s; converge block-wide.
            // NOTE: this wait also (a) drains our older stores via in-order vmcnt and
            // (b) its exit barrier orders all waves past their step-(t-1) MFMA reads,
            // making the ds_writes below safe.
            for (;;) {
                unsigned bad = 0;
                #pragma unroll
                for (int j = 0; j < 8; ++j)
                    bad |= (unsigned)((u32)A[j] == SENT32) |
                           (unsigned)((u32)(A[j] >> 32) == SENT32);
                if (!__syncthreads_or((int)bad)) break;
                #pragma unroll
                for (int j = 0; j < 8; ++j)
                    if (((u32)A[j] == SENT32) || ((u32)(A[j] >> 32) == SENT32))
                        A[j] = __hip_atomic_load((const u64*)(src + (size_t)j * 4096),
                                                 __ATOMIC_RELAXED, __HIP_MEMORY_SCOPE_AGENT);
            }
            // stage into swizzled LDS
            #pragma unroll
            for (int j = 0; j < 8; ++j) {
                int row = srow0 + j * 2;
                *(u64*)(Hsh + row * 2048 + (sk2 ^ ((row & 7) << 4))) = A[j];
            }
            __syncthreads();   // staging complete

            // ---- 32 MFMAs: A from swizzled LDS, B from registers ----
            #pragma unroll
            for (int u = 0; u < 32; ++u) {
                f16x8 af = *(const f16x8*)(Hsh + abase + ((u * 64 + quad * 16) ^ axor));
                acc[u & 3] = __builtin_amdgcn_mfma_f32_16x16x32_f16(af, bfr[u], acc[u & 3], 0, 0, 0);
            }
        }

        // epilogue: compute h and publish per-element ASAP (fire-and-forget coherent
        // stores — the END of the producer critical path; no drain, no flag, no barrier)
        char* hwp = hb + (size_t)(t & 7) * 65536 + (size_t)(hwrow - hb);
        float hv[4];
        #pragma unroll
        for (int i = 0; i < 4; ++i) {
            float z = (acc[0][i] + acc[1][i]) + (acc[2][i] + acc[3][i]) + wh[i];
            float e = __expf(2.0f * z);
            hv[i] = 1.0f - 2.0f * __builtin_amdgcn_rcpf(e + 1.0f);
            if (t < TT - 1) {
                f16 hh = (f16)hv[i];
                unsigned short hbits = __builtin_bit_cast(unsigned short, hh);
                int other = __shfl_xor((int)hbits, 1, 64);   // partner col (l15 ^ 1)
                if ((lane & 1) == 0) {
                    unsigned int packed = (unsigned int)hbits | ((unsigned int)other << 16);
                    __hip_atomic_store((unsigned int*)(hwp + (size_t)i * 2048), packed,
                                       __ATOMIC_RELAXED, __HIP_MEMORY_SCOPE_AGENT);
                }
            }
        }
        __builtin_amdgcn_sched_barrier(0);   // keep re-sentinel/out stores below publish

        // re-sentinel own cells of slot (t+3)&7 (written at t+3, last read at t-4;
        // acked before our next staging wait -> ordered before any future data write).
        if (t < TT - 4 && (lane & 1) == 0) {
            char* hri = hb + (size_t)((t + 3) & 7) * 65536 + (size_t)(hwrow - hb);
            #pragma unroll
            for (int i = 0; i < 4; ++i)
                __hip_atomic_store((unsigned int*)(hri + (size_t)i * 2048), SENT32,
                                   __ATOMIC_RELAXED, __HIP_MEMORY_SCOPE_AGENT);
        }

        // fp32 h -> d_out, off every critical path (drains under next staging wait)
        #pragma unroll
        for (int i = 0; i < 4; ++i) out[obase + (size_t)i * DD] = hv[i];
    }
}

extern "C" void kernel_launch(void* const* d_in, const int* in_sizes, int n_in,
                              void* d_out, int out_size, void* d_ws, size_t ws_size,
                              hipStream_t stream)
{
    const float* x  = (const float*)d_in[0];
    const float* wr = (const float*)d_in[1];
    const float* wi = (const float*)d_in[2];
    const float* wj = (const float*)d_in[3];
    const float* wk = (const float*)d_in[4];
    const float* ur = (const float*)d_in[5];
    const float* ui = (const float*)d_in[6];
    const float* uj = (const float*)d_in[7];
    const float* uk = (const float*)d_in[8];
    const float* bias = (const float*)d_in[9];
    float* out = (float*)d_out;

    char* ws = (char*)d_ws;
    f16* WhT  = (f16*)(ws);                          // 2 MB
    f16* UhT  = (f16*)(ws + (1 << 21));              // 2 MB
    unsigned int* hbuf = (unsigned int*)(ws + (1 << 22));   // 8 x 64 KB ring

    hipLaunchKernelGGL(qrnn_prep, dim3(8320), dim3(256), 0, stream,
                       wr, wi, wj, wk, ur, ui, uj, uk, WhT, UhT, hbuf);
    hipLaunchKernelGGL(qrnn_gemm, dim3(8, 128), dim3(256), 0, stream,
                       x, WhT, bias, out);
    hipLaunchKernelGGL(qrnn_scan, dim3(16), dim3(512), 0, stream,
                       UhT, hbuf, out);
}

// Round 10
// 1966.691 us; speedup vs baseline: 1.7154x; 1.0713x over previous
//
#include <hip/hip_runtime.h>

// QRNN: T=512, B=32, D=1024, Q=256.
//  Phase A (prep):  build WhT/UhT fp16 [e][d] (transposed); fill hbuf ring with sentinel.
//  Phase B (gemm):  wh_out = x @ Wh + b  -> written fp32 into d_out (overwritten by scan).
//  Phase C (scan):  h_t = tanh(wh_out[t] + h_{t-1} @ Uh), in-place on d_out.
//  R11 = R10 (staged 16-WG topology + sentinel handshake, 1915us scan) with the detect
//        loop converted from block-rendezvous to PER-THREAD SPIN:
//    * Each thread's 8 staged u64s live in one 4-col slice -> exactly ONE producer WG.
//      Thread spins privately (dependent reload of only its bad u64s), then ONE barrier
//      before ds_write. R10's __syncthreads_or retry made every straggler cell cost a
//      full 512-thread round (reload+or+barrier ~0.5-0.7us); now it costs one dependent
//      reload RT on the affected threads only. Barriers/step: 2 (unchanged minimum).
//    * The pre-ds_write barrier still provides prev-step-MFMA-reads-complete ordering
//      and keeps the <=1-step cross-WG skew bound -> ring-reuse argument unchanged
//      (8 slots, distance-3 re-sentinel; correctness-proven R3/R6/R10).
//    * Staging loads issued BEFORE wh loads (critical stream first).
//  All inter-WG traffic via per-access coherent atomics (sc0 sc1 -> LLC). No agent fences.

#define TT 512
#define BB 32
#define DD 1024
#define SENT32 0x7E007E00u

typedef _Float16 f16;
typedef _Float16 f16x8 __attribute__((ext_vector_type(8)));
typedef _Float16 f16x4 __attribute__((ext_vector_type(4)));
typedef float f32x4 __attribute__((ext_vector_type(4)));
typedef unsigned int u32;
typedef unsigned long long u64;

__device__ __constant__ int   QCOMP[4][4] = {{0,1,2,3},{1,0,3,2},{2,3,0,1},{3,2,1,0}};
__device__ __constant__ float QSIGN[4][4] = {{ 1.f, 1.f, 1.f, 1.f},
                                             {-1.f, 1.f, 1.f,-1.f},
                                             {-1.f,-1.f, 1.f, 1.f},
                                             {-1.f, 1.f,-1.f, 1.f}};

__device__ __forceinline__ float qpick(int cmp, const float* a, const float* b,
                                       const float* c, const float* d, int idx) {
    const float* s = (cmp == 0) ? a : (cmp == 1) ? b : (cmp == 2) ? c : d;
    return s[idx];
}

// ---------------- Phase A -------------------------------------------------------------
__global__ void qrnn_prep(const float* __restrict__ wr, const float* __restrict__ wi,
                          const float* __restrict__ wj, const float* __restrict__ wk,
                          const float* __restrict__ ur, const float* __restrict__ ui,
                          const float* __restrict__ uj, const float* __restrict__ uk,
                          f16* __restrict__ WhT, f16* __restrict__ UhT,
                          unsigned int* __restrict__ hbuf)
{
    int bid = blockIdx.x;
    int gid = bid * 256 + threadIdx.x;
    if (bid < 4096) {                    // WhT: 1M elements, flat = e*1024 + d
        int e = gid >> 10, d = gid & 1023;
        int bc = e >> 8, j = e & 255, br = d >> 8, i = d & 255;
        float v = QSIGN[br][bc] * qpick(QCOMP[br][bc], wr, wi, wj, wk, i * 256 + j);
        WhT[gid] = (f16)v;
    } else if (bid < 8192) {             // UhT
        int g = gid - 4096 * 256;
        int e = g >> 10, d = g & 1023;
        int bc = e >> 8, j = e & 255, br = d >> 8, i = d & 255;
        float v = QSIGN[br][bc] * qpick(QCOMP[br][bc], ur, ui, uj, uk, i * 256 + j);
        UhT[g] = (f16)v;
    } else {                             // hbuf sentinel fill: 8 slots x 64KB = 32768 uint4
        int g = gid - 8192 * 256;
        if (g < 32768) {
            uint4 s = {SENT32, SENT32, SENT32, SENT32};
            ((uint4*)hbuf)[g] = s;
        }
    }
}

// ---------------- Phase B: wh_out = x @ Wh + bias ------------------------------------
__global__ __launch_bounds__(256) void qrnn_gemm(const float* __restrict__ x,
                                                 const f16* __restrict__ WhT,
                                                 const float* __restrict__ bias,
                                                 float* __restrict__ out)
{
    __shared__ f16 Ash[128][72];
    __shared__ f16 Bsh[128][72];

    const int tn = blockIdx.x, tm = blockIdx.y;
    const int tid = threadIdx.x;
    const int lane = tid & 63, w = tid >> 6;
    const int wm = (w >> 1) * 64, wn = (w & 1) * 64;
    const int m0 = tm * 128, n0 = tn * 128;
    const int l15 = lane & 15, q8 = (lane >> 4) * 8;

    f32x4 acc[4][4] = {};

    const int arow = tid >> 4;
    const int acol = (tid & 15) * 4;
    const int brow = tid >> 3;
    const int bcol = (tid & 7) * 8;

    for (int kb = 0; kb < DD; kb += 64) {
        #pragma unroll
        for (int p = 0; p < 8; ++p) {
            int rrow = p * 16 + arow;
            float4 v = *(const float4*)(x + (size_t)(m0 + rrow) * DD + kb + acol);
            f16x4 hv = {(f16)v.x, (f16)v.y, (f16)v.z, (f16)v.w};
            *(f16x4*)&Ash[rrow][acol] = hv;
        }
        #pragma unroll
        for (int p = 0; p < 4; ++p) {
            int rn = p * 32 + brow;
            f16x8 v = *(const f16x8*)(WhT + (size_t)(n0 + rn) * DD + kb + bcol);
            *(f16x8*)&Bsh[rn][bcol] = v;
        }
        __syncthreads();
        #pragma unroll
        for (int ks = 0; ks < 64; ks += 32) {
            f16x8 af[4], bf[4];
            #pragma unroll
            for (int i = 0; i < 4; ++i) af[i] = *(const f16x8*)&Ash[wm + i * 16 + l15][ks + q8];
            #pragma unroll
            for (int i = 0; i < 4; ++i) bf[i] = *(const f16x8*)&Bsh[wn + i * 16 + l15][ks + q8];
            #pragma unroll
            for (int i = 0; i < 4; ++i)
                #pragma unroll
                for (int j = 0; j < 4; ++j)
                    acc[i][j] = __builtin_amdgcn_mfma_f32_16x16x32_f16(af[i], bf[j], acc[i][j], 0, 0, 0);
        }
        __syncthreads();
    }
    const int quad = lane >> 4;
    #pragma unroll
    for (int i = 0; i < 4; ++i)
        #pragma unroll
        for (int j = 0; j < 4; ++j) {
            int col = n0 + wn + j * 16 + l15;
            float bz = bias[col];
            #pragma unroll
            for (int rr = 0; rr < 4; ++rr) {
                int row = m0 + wm + i * 16 + quad * 4 + rr;
                out[(size_t)row * DD + col] = acc[i][j][rr] + bz;
            }
        }
}

// ---------------- Phase C: sequential scan (staged + sentinel + per-thread spin) -----
// WG (rg,cg): batch rows [16rg,16rg+16), cols [128cg,128cg+128). 8 waves x 16 cols.
// Ring: 8 slots x 64KB, slot layout [32 rows][1024 cols] fp16; rg offset = rg*32768.
__global__ __launch_bounds__(512, 2) void qrnn_scan(const f16* __restrict__ UhT,
                                                    unsigned int* __restrict__ hbuf,
                                                    float* __restrict__ out)
{
    __shared__ u64 HshQ[4096];              // 32KB: h block, XOR-swizzled rows
    char* Hsh = (char*)HshQ;

    const int rg = blockIdx.x >> 3;         // row group 0..1
    const int cg = blockIdx.x & 7;          // col group 0..7
    const int tid = threadIdx.x;
    const int w = tid >> 6, lane = tid & 63;
    const int l15 = lane & 15, quad = lane >> 4, q8 = quad * 8;
    const int dcol = cg * 128 + w * 16 + l15;   // output feature col
    const int bq = rg * 16 + quad * 4;          // first output batch row of this frag

    // ---- one-time: Uh B-fragments into registers/AGPRs (16 cols x 1024 k per wave) ----
    f16x8 bfr[32];
    {
        const f16* ub = UhT + (size_t)dcol * DD;
        #pragma unroll
        for (int u = 0; u < 32; ++u)
            bfr[u] = *(const f16x8*)(ub + u * 32 + q8);
    }

    char* hb = (char*)hbuf;
    char* hwrow = hb + (size_t)(bq * 1024 + (dcol & ~1)) * 2;   // packed u32 store base

    // staging geometry: thread j-th u64 at slot + rg*32768 + tid*8 + j*4096
    // -> thread's 8 cells: rows (tid>>8)+j*2, a single 4-col slice (tid&255)*4
    //    => one producer WG per thread (cg = ((tid&255)*4)>>7).
    const size_t sbase = (size_t)rg * 32768 + (size_t)tid * 8;
    const int srow0 = tid >> 8;                 // dest row = srow0 + j*2
    const int sk2   = (tid & 255) * 8;          // byte offset within row

    // A-frag read geometry: row = l15, k-bytes = u*64 + quad*16, XOR (row&7)<<4
    const int abase = l15 * 2048;
    const int axor  = (l15 & 7) << 4;

    #pragma unroll 1
    for (int t = 0; t < TT; ++t) {
        const size_t obase = (size_t)t * (BB * DD) + (size_t)bq * DD + dcol;

        f32x4 acc[4] = {};
        float wh[4];
        if (t > 0) {
            // staging loads FIRST (critical stream), wh after (retires under the spin)
            const char* src = hb + (size_t)((t - 1) & 7) * 65536 + sbase;
            u64 A[8];
            #pragma unroll
            for (int j = 0; j < 8; ++j)
                A[j] = __hip_atomic_load((const u64*)(src + (size_t)j * 4096),
                                         __ATOMIC_RELAXED, __HIP_MEMORY_SCOPE_AGENT);
            #pragma unroll
            for (int i = 0; i < 4; ++i) wh[i] = out[obase + (size_t)i * DD];

            // per-thread spin: reload only own bad u64s; no block rendezvous per round
            for (;;) {
                unsigned bad = 0;
                #pragma unroll
                for (int j = 0; j < 8; ++j)
                    bad |= (unsigned)((u32)A[j] == SENT32) |
                           (unsigned)((u32)(A[j] >> 32) == SENT32);
                if (!bad) break;
                #pragma unroll
                for (int j = 0; j < 8; ++j)
                    if (((u32)A[j] == SENT32) || ((u32)(A[j] >> 32) == SENT32))
                        A[j] = __hip_atomic_load((const u64*)(src + (size_t)j * 4096),
                                                 __ATOMIC_RELAXED, __HIP_MEMORY_SCOPE_AGENT);
            }

            // one barrier: all threads validated AND all waves' prev-step MFMA LDS
            // reads are complete (program order) -> safe to overwrite Hsh.
            __syncthreads();

            // stage into swizzled LDS
            #pragma unroll
            for (int j = 0; j < 8; ++j) {
                int row = srow0 + j * 2;
                *(u64*)(Hsh + row * 2048 + (sk2 ^ ((row & 7) << 4))) = A[j];
            }
            __syncthreads();   // staging complete

            // ---- 32 MFMAs: A from swizzled LDS, B from registers ----
            #pragma unroll
            for (int u = 0; u < 32; ++u) {
                f16x8 af = *(const f16x8*)(Hsh + abase + ((u * 64 + quad * 16) ^ axor));
                acc[u & 3] = __builtin_amdgcn_mfma_f32_16x16x32_f16(af, bfr[u], acc[u & 3], 0, 0, 0);
            }
        } else {
            #pragma unroll
            for (int i = 0; i < 4; ++i) wh[i] = out[obase + (size_t)i * DD];
        }

        // epilogue: compute h and publish per-element ASAP (fire-and-forget coherent
        // stores — the END of the producer critical path; no drain, no flag, no barrier)
        char* hwp = hb + (size_t)(t & 7) * 65536 + (size_t)(hwrow - hb);
        float hv[4];
        #pragma unroll
        for (int i = 0; i < 4; ++i) {
            float z = (acc[0][i] + acc[1][i]) + (acc[2][i] + acc[3][i]) + wh[i];
            float e = __expf(2.0f * z);
            hv[i] = 1.0f - 2.0f * __builtin_amdgcn_rcpf(e + 1.0f);
            if (t < TT - 1) {
                f16 hh = (f16)hv[i];
                unsigned short hbits = __builtin_bit_cast(unsigned short, hh);
                int other = __shfl_xor((int)hbits, 1, 64);   // partner col (l15 ^ 1)
                if ((lane & 1) == 0) {
                    unsigned int packed = (unsigned int)hbits | ((unsigned int)other << 16);
                    __hip_atomic_store((unsigned int*)(hwp + (size_t)i * 2048), packed,
                                       __ATOMIC_RELAXED, __HIP_MEMORY_SCOPE_AGENT);
                }
            }
        }
        __builtin_amdgcn_sched_barrier(0);   // keep re-sentinel/out stores below publish

        // re-sentinel own cells of slot (t+3)&7 (written at t+3, last read at t-4;
        // acked before our next staging wait -> ordered before any future data write).
        if (t < TT - 4 && (lane & 1) == 0) {
            char* hri = hb + (size_t)((t + 3) & 7) * 65536 + (size_t)(hwrow - hb);
            #pragma unroll
            for (int i = 0; i < 4; ++i)
                __hip_atomic_store((unsigned int*)(hri + (size_t)i * 2048), SENT32,
                                   __ATOMIC_RELAXED, __HIP_MEMORY_SCOPE_AGENT);
        }

        // fp32 h -> d_out, off every critical path (drains under next staging wait)
        #pragma unroll
        for (int i = 0; i < 4; ++i) out[obase + (size_t)i * DD] = hv[i];
    }
}

extern "C" void kernel_launch(void* const* d_in, const int* in_sizes, int n_in,
                              void* d_out, int out_size, void* d_ws, size_t ws_size,
                              hipStream_t stream)
{
    const float* x  = (const float*)d_in[0];
    const float* wr = (const float*)d_in[1];
    const float* wi = (const float*)d_in[2];
    const float* wj = (const float*)d_in[3];
    const float* wk = (const float*)d_in[4];
    const float* ur = (const float*)d_in[5];
    const float* ui = (const float*)d_in[6];
    const float* uj = (const float*)d_in[7];
    const float* uk = (const float*)d_in[8];
    const float* bias = (const float*)d_in[9];
    float* out = (float*)d_out;

    char* ws = (char*)d_ws;
    f16* WhT  = (f16*)(ws);                          // 2 MB
    f16* UhT  = (f16*)(ws + (1 << 21));              // 2 MB
    unsigned int* hbuf = (unsigned int*)(ws + (1 << 22));   // 8 x 64 KB ring

    hipLaunchKernelGGL(qrnn_prep, dim3(8320), dim3(256), 0, stream,
                       wr, wi, wj, wk, ur, ui, uj, uk, WhT, UhT, hbuf);
    hipLaunchKernelGGL(qrnn_gemm, dim3(8, 128), dim3(256), 0, stream,
                       x, WhT, bias, out);
    hipLaunchKernelGGL(qrnn_scan, dim3(16), dim3(512), 0, stream,
                       UhT, hbuf, out);
}